// Round 12
// baseline (118.939 us; speedup 1.0000x reference)
//
#include <hip/hip_runtime.h>
#include <hip/hip_bf16.h>

typedef float f32x4 __attribute__((ext_vector_type(4)));
typedef float f32x16 __attribute__((ext_vector_type(16)));
typedef __bf16 bf16x8 __attribute__((ext_vector_type(8)));
typedef __bf16 bf16x4 __attribute__((ext_vector_type(4)));
typedef unsigned int uint2v __attribute__((ext_vector_type(2)));
typedef unsigned int u32;

constexpr int B_ = 8, C_ = 256, N_ = 2048, H_ = 4, D_ = 64;
constexpr int BH_ = B_ * H_;  // 32
constexpr size_t PER_ = (size_t)BH_ * N_ * D_;  // 4M elems
constexpr float LOG2E = 1.44269504088896340736f;

static __device__ __forceinline__ float fast_exp2(float x) {
#if __has_builtin(__builtin_amdgcn_exp2f)
  return __builtin_amdgcn_exp2f(x);
#else
  return exp2f(x);
#endif
}

// XOR swizzle for [rows][128B] tiles: spread 16B slots across banks.
static __device__ __forceinline__ void* swz(void* base, int row, int cb) {
  return (char*)base + row * 128 + (cb ^ ((row & 7) << 4));
}
static __device__ __forceinline__ const void* swz(const void* base, int row, int cb) {
  return (const char*)base + row * 128 + (cb ^ ((row & 7) << 4));
}

// async global->LDS, 16B per lane. LDS dst: wave-uniform base + lane*16.
static __device__ __forceinline__ void gload16(void* lds, const void* g) {
  __builtin_amdgcn_global_load_lds(
      (const __attribute__((address_space(1))) u32*)g,
      (__attribute__((address_space(3))) u32*)lds, 16, 0, 0);
}

// ---------------------------------------------------------------------------
// W pre-convert -> bf16 A-fragment order (16x16 frags for the GEMM kernels).
// ---------------------------------------------------------------------------
struct W4 {
  const float* s0; const float* s1; const float* s2; const float* s3;
  __bf16* d0; __bf16* d1; __bf16* d2; __bf16* d3;
};

__global__ __launch_bounds__(256) void wcvt_kernel(W4 p) {
  const int m = blockIdx.y;
  const float* src = m == 0 ? p.s0 : m == 1 ? p.s1 : m == 2 ? p.s2 : p.s3;
  __bf16* dst = m == 0 ? p.d0 : m == 1 ? p.d1 : m == 2 ? p.d2 : p.d3;
  const int f = blockIdx.x * 256 + threadIdx.x;  // 0..8191 fragment ids
  const int o_blk = f >> 9;
  const int ks = (f >> 6) & 7;
  const int lane = f & 63;
  const int row = o_blk * 16 + (lane & 15);
  const int kbase = ks * 32 + (lane >> 4) * 8;
  bf16x8 v;
  if (m == 3) {
    for (int e = 0; e < 8; e++) {
      const int k = kbase + e;
      const int c = ((k & 63) << 2) | (k >> 6);
      v[e] = (__bf16)src[row * 256 + c];
    }
  } else {
    const int srow = ((row & 63) << 2) | (row >> 6);  // orig channel d*4+h
    const float* s = src + srow * 256 + kbase;
    float4 a = *(const float4*)s;
    float4 b = *(const float4*)(s + 4);
    v[0] = (__bf16)a.x; v[1] = (__bf16)a.y; v[2] = (__bf16)a.z; v[3] = (__bf16)a.w;
    v[4] = (__bf16)b.x; v[5] = (__bf16)b.y; v[6] = (__bf16)b.z; v[7] = (__bf16)b.w;
  }
  *(bf16x8*)&dst[(size_t)f * 8] = v;
}

// ---------------------------------------------------------------------------
// Fused QKV projection. X staged transposed in LDS (packed k-pair b32
// writes). Q -> row-major [bh][n][64] bf16 (scaled, exp2 dom) direct.
// K,V^T -> swizzled 8KB tile IMAGES built in LDS (scatter-friendly), then
// streamed to global as fully-coalesced 16B stores (4 head-tiles/block).
// ---------------------------------------------------------------------------
__global__ __launch_bounds__(256) void qkv_fused_kernel(
    const float* __restrict__ xq, const float* __restrict__ xk,
    const float* __restrict__ xv, const __bf16* __restrict__ wfq,
    const __bf16* __restrict__ wfk, const __bf16* __restrict__ wfv,
    const float* __restrict__ bq, const float* __restrict__ bk,
    const float* __restrict__ bv, __bf16* __restrict__ oq,
    char* __restrict__ oksw, char* __restrict__ ovsw) {
  __shared__ union {
    __bf16 xlds[64][264];  // staging: [n][k] padded
    char img[32768];       // output: 4 x 8KB swizzled head-tiles
  } sh;

  const int m = blockIdx.x >> 8;
  int inner = blockIdx.x & 255;
  inner = (inner & 7) * 32 + (inner >> 3);  // bijective XCD swizzle (256=8*32)
  const int b = inner >> 5, nb = inner & 31;
  const int n0 = nb * 64;

  const float* xf = m == 0 ? xq : m == 1 ? xk : xv;
  const __bf16* wf = m == 0 ? wfq : m == 1 ? wfk : wfv;
  const float* bias = m == 0 ? bq : m == 1 ? bk : bv;
  const float scale = m == 0 ? 0.125f * LOG2E : 1.0f;

  const int t = threadIdx.x;
  {
    const int kl = t & 15;          // k-pair id
    const int nl = (t >> 4) * 4;    // n base
    const float* src = xf + (size_t)b * C_ * N_ + n0 + nl;
    for (int kp = 0; kp < 8; kp++) {
      const int k = kp * 32 + kl * 2;
      float4 f0 = *(const float4*)(src + (size_t)k * N_);
      float4 f1 = *(const float4*)(src + (size_t)(k + 1) * N_);
      union { __bf16 h[2]; u32 u; } c0, c1, c2, c3;
      c0.h[0] = (__bf16)f0.x; c0.h[1] = (__bf16)f1.x;
      c1.h[0] = (__bf16)f0.y; c1.h[1] = (__bf16)f1.y;
      c2.h[0] = (__bf16)f0.z; c2.h[1] = (__bf16)f1.z;
      c3.h[0] = (__bf16)f0.w; c3.h[1] = (__bf16)f1.w;
      *(u32*)&sh.xlds[nl + 0][k] = c0.u;
      *(u32*)&sh.xlds[nl + 1][k] = c1.u;
      *(u32*)&sh.xlds[nl + 2][k] = c2.u;
      *(u32*)&sh.xlds[nl + 3][k] = c3.u;
    }
  }
  __syncthreads();

  const int lane = t & 63, wvv = t >> 6;
  const int wm = wvv >> 1, wn = wvv & 1;   // wave: 128 o x 32 n
  const int l15 = lane & 15, lg = lane >> 4;

  f32x4 acc[8][2] = {};

  for (int ks = 0; ks < 8; ks++) {
    bf16x8 bfr[2];
    for (int ni = 0; ni < 2; ni++)
      bfr[ni] = *(const bf16x8*)&sh.xlds[wn * 32 + ni * 16 + l15][ks * 32 + lg * 8];
    for (int mi = 0; mi < 8; mi++) {
      bf16x8 af = *(const bf16x8*)&wf[(((size_t)(wm * 8 + mi) * 8 + ks) * 64 + lane) * 8];
      acc[mi][0] = __builtin_amdgcn_mfma_f32_16x16x32_bf16(af, bfr[0], acc[mi][0], 0, 0, 0);
      acc[mi][1] = __builtin_amdgcn_mfma_f32_16x16x32_bf16(af, bfr[1], acc[mi][1], 0, 0, 0);
    }
  }

  if (m == 0) {
    // Q: direct stores, [bh][n][64], 8B chunks forming 32B runs
    for (int mi = 0; mi < 8; mi++) {
      const int h = wm * 2 + (mi >> 2);
      const int d0 = (mi & 3) * 16 + 4 * lg;
      for (int ni = 0; ni < 2; ni++) {
        const int n = n0 + wn * 32 + ni * 16 + l15;
        bf16x4 o4;
        for (int r = 0; r < 4; r++)
          o4[r] = (__bf16)((acc[mi][ni][r] + bias[((d0 + r) << 2) | h]) * scale);
        *(bf16x4*)&oq[((size_t)(b * H_ + h) * N_ + n) * D_ + d0] = o4;
      }
    }
  } else {
    __syncthreads();  // done reading xlds; rebuild as output image
    for (int mi = 0; mi < 8; mi++) {
      const int h = wm * 2 + (mi >> 2);
      const int d0 = (mi & 3) * 16 + 4 * lg;
      char* himg = sh.img + h * 8192;
      for (int ni = 0; ni < 2; ni++) {
        const int nl = wn * 32 + ni * 16 + l15;  // n & 63
        if (m == 1) {
          bf16x4 o4;
          for (int r = 0; r < 4; r++)
            o4[r] = (__bf16)(acc[mi][ni][r] + bias[((d0 + r) << 2) | h]);
          *(bf16x4*)swz(himg, nl, 2 * d0) = o4;
        } else {
          for (int r = 0; r < 4; r++)
            *(__bf16*)swz(himg, d0 + r, 2 * nl) =
                (__bf16)(acc[mi][ni][r] + bias[((d0 + r) << 2) | h]);
        }
      }
    }
    __syncthreads();
    char* outt = (m == 1) ? oksw : ovsw;
#pragma unroll
    for (int h = 0; h < 4; h++) {
      const size_t tb = ((size_t)(b * H_ + h) * (N_ / 64) + nb) * 8192;
      *(uint4*)(outt + tb + t * 32) = *(const uint4*)(sh.img + h * 8192 + t * 32);
      *(uint4*)(outt + tb + t * 32 + 16) =
          *(const uint4*)(sh.img + h * 8192 + t * 32 + 16);
    }
  }
}

// ---------------------------------------------------------------------------
// Final projection, NS-way COMBINE fused: xhat = (sum_s p_s)/(sum_s l_s)
// computed in registers per B-fragment. NS==1: p already normalized.
// ---------------------------------------------------------------------------
template <int NS>
__global__ __launch_bounds__(256) void final_proj_kernel(
    const __bf16* __restrict__ p, const float* __restrict__ lb,
    const __bf16* __restrict__ wf, const float* __restrict__ bias,
    float* __restrict__ out) {
  const int bid = blockIdx.x;
  const int wid = (bid & 7) * 128 + (bid >> 3);
  const int o_t = wid & 3;
  const int nb = (wid >> 2) & 31;
  const int b = wid >> 7;
  const int o0 = o_t * 64, n0 = nb * 64;
  const int t = threadIdx.x, lane = t & 63;
  const int wvv = t >> 6, wm = wvv >> 1, wn = wvv & 1;
  const int l15 = lane & 15, lg = lane >> 4;
  const int nbase = n0 + wn * 32 + l15;

  float inv[2][4];  // [ni][h]
  if constexpr (NS > 1) {
    for (int ni = 0; ni < 2; ni++)
      for (int h = 0; h < 4; h++) {
        const size_t bhn = (size_t)(b * H_ + h) * N_ + nbase + ni * 16;
        float ls = 0.f;
#pragma unroll
        for (int u = 0; u < NS; u++) ls += lb[(size_t)u * BH_ * N_ + bhn];
        inv[ni][h] = 1.f / ls;
      }
  }

  f32x4 acc[2][2] = {};

  for (int ks = 0; ks < 8; ks++) {
    bf16x8 af[2];
    for (int mi = 0; mi < 2; mi++)
      af[mi] = *(const bf16x8*)&wf[(((size_t)(o_t * 4 + wm * 2 + mi) * 8 + ks) * 64 + lane) * 8];
    bf16x8 bfr[2];
    const int h = ks >> 1;
    const size_t bh = (size_t)(b * H_ + h);
    const int d0 = (ks & 1) * 32 + lg * 8;
    for (int ni = 0; ni < 2; ni++) {
      const size_t off = (bh * N_ + nbase + ni * 16) * D_ + d0;
      if constexpr (NS == 1) {
        bfr[ni] = *(const bf16x8*)&p[off];
      } else {
        float s8[8] = {};
#pragma unroll
        for (int u = 0; u < NS; u++) {
          bf16x8 a = *(const bf16x8*)&p[(size_t)u * PER_ + off];
#pragma unroll
          for (int e = 0; e < 8; e++) s8[e] += (float)a[e];
        }
        const float iv = inv[ni][h];
        bf16x8 r;
#pragma unroll
        for (int e = 0; e < 8; e++) r[e] = (__bf16)(s8[e] * iv);
        bfr[ni] = r;
      }
    }
    for (int mi = 0; mi < 2; mi++)
      for (int ni = 0; ni < 2; ni++)
        acc[mi][ni] = __builtin_amdgcn_mfma_f32_16x16x32_bf16(
            af[mi], bfr[ni], acc[mi][ni], 0, 0, 0);
  }

  for (int mi = 0; mi < 2; mi++) {
    for (int r = 0; r < 4; r++) {
      const int och = o0 + wm * 32 + mi * 16 + 4 * lg + r;
      const float bv_ = bias[och];
      for (int ni = 0; ni < 2; ni++) {
        const int n = n0 + wn * 32 + ni * 16 + l15;
        out[((size_t)b * C_ + och) * N_ + n] = acc[mi][ni][r] + bv_;
      }
    }
  }
}

// ---------------------------------------------------------------------------
// Flash attention (round-8 proven shape, unchanged): 8 waves x 32 q,
// 512 thr; async global_load_lds from pre-swizzled tiles, double-buffered.
// 32x32 MFMA, in-register P (permlane32_swap), maxless softmax (exp2 dom).
// ---------------------------------------------------------------------------
template <int SPLIT>
__global__ __launch_bounds__(512) void attn_kernel(
    const __bf16* __restrict__ qb, const char* __restrict__ kbsw,
    const char* __restrict__ vtsw, __bf16* __restrict__ pO,
    float* __restrict__ lbuf) {
  __shared__ char smem[32768];  // K dbuf 2x8KB @0, V dbuf 2x8KB @16384

  const int t = threadIdx.x, lane = t & 63, wv = t >> 6;  // wv 0..7
  const int l31 = lane & 31, hi = lane >> 5;

  const int bid = blockIdx.x;  // 256*SPLIT blocks
  const int per_xcd = (256 * SPLIT) / 8;
  const int wid = (bid & 7) * per_xcd + (bid >> 3);  // 4 bh per XCD
  const int bh = wid / (8 * SPLIT);
  const int rem = wid % (8 * SPLIT);
  const int qt = rem % 8;
  const int s = rem / 8;
  const int qn = qt * 256 + wv * 32;  // wave's 32 q rows
  constexpr int NT = N_ / SPLIT / 64; // tiles per block
  const int jt0 = s * NT;

  const char* ktiles = kbsw + (size_t)bh * (N_ / 64) * 8192;
  const char* vtiles = vtsw + (size_t)bh * (N_ / 64) * 8192;

  // Q B-frags: qf[i] = Q[q=qn+l31][d = i*16 + hi*8 .. +7]
  const __bf16* qrow = qb + ((size_t)bh * N_ + qn + l31) * D_;
  bf16x8 qf[4];
#pragma unroll
  for (int i = 0; i < 4; i++) qf[i] = *(const bf16x8*)(qrow + i * 16 + hi * 8);

  // stage tile jt_g into buffer bb (2 async 16B loads/thread, 512 thr)
  auto stage = [&](int jt_g, int bb) {
    gload16(smem + bb * 8192 + t * 16, ktiles + (size_t)jt_g * 8192 + t * 16);
    gload16(smem + 16384 + bb * 8192 + t * 16,
            vtiles + (size_t)jt_g * 8192 + t * 16);
  };

  stage(jt0, 0);
  __syncthreads();  // drains vmcnt -> tile 0 resident

  f32x16 o0 = {}, o1 = {};
  float la0 = 0.f, la1 = 0.f, la2 = 0.f, la3 = 0.f;
  int cur = 0;

  for (int jt = 0; jt < NT; jt++) {
    if (jt + 1 < NT) stage(jt0 + jt + 1, cur ^ 1);
    const char* kc = smem + cur * 8192;
    const char* vc = smem + 16384 + cur * 8192;

    // QK: two 32x32 S-subtiles
    f32x16 s0 = {}, s1 = {};
    __builtin_amdgcn_s_setprio(1);
#pragma unroll
    for (int i = 0; i < 4; i++) {
      bf16x8 kf = *(const bf16x8*)swz(kc, l31, i * 32 + hi * 16);
      s0 = __builtin_amdgcn_mfma_f32_32x32x16_bf16(kf, qf[i], s0, 0, 0, 0);
    }
#pragma unroll
    for (int i = 0; i < 4; i++) {
      bf16x8 kf = *(const bf16x8*)swz(kc, 32 + l31, i * 32 + hi * 16);
      s1 = __builtin_amdgcn_mfma_f32_32x32x16_bf16(kf, qf[i], s1, 0, 0, 0);
    }
    __builtin_amdgcn_s_setprio(0);

    // per-subtile: exp2 -> pack bf16 pairs -> permlane32_swap -> PV
#pragma unroll
    for (int sub = 0; sub < 2; sub++) {
      const f32x16 sv = sub ? s1 : s0;
      float pr[16];
#pragma unroll
      for (int r = 0; r < 16; r++) pr[r] = fast_exp2(sv[r]);
      la0 += pr[0] + pr[4] + pr[8] + pr[12];
      la1 += pr[1] + pr[5] + pr[9] + pr[13];
      la2 += pr[2] + pr[6] + pr[10] + pr[14];
      la3 += pr[3] + pr[7] + pr[11] + pr[15];
      unsigned w[8];
#pragma unroll
      for (int g = 0; g < 8; g++) {
        union { __bf16 h[2]; unsigned u; } cv;
        cv.h[0] = (__bf16)pr[2 * g];
        cv.h[1] = (__bf16)pr[2 * g + 1];
        w[g] = cv.u;
      }
      uint2v r0 = __builtin_amdgcn_permlane32_swap(w[0], w[2], false, false);
      uint2v r1 = __builtin_amdgcn_permlane32_swap(w[1], w[3], false, false);
      uint2v r2 = __builtin_amdgcn_permlane32_swap(w[4], w[6], false, false);
      uint2v r3 = __builtin_amdgcn_permlane32_swap(w[5], w[7], false, false);
      union { unsigned u[4]; bf16x8 v; } f0 = {{r0.x, r1.x, r0.y, r1.y}};  // k 0..15
      union { unsigned u[4]; bf16x8 v; } f1 = {{r2.x, r3.x, r2.y, r3.y}};  // k 16..31
      const int scb = sub * 64;
      __builtin_amdgcn_s_setprio(1);
      {
        bf16x8 vf = *(const bf16x8*)swz(vc, l31, scb + hi * 16);
        o0 = __builtin_amdgcn_mfma_f32_32x32x16_bf16(vf, f0.v, o0, 0, 0, 0);
        vf = *(const bf16x8*)swz(vc, l31, scb + 32 + hi * 16);
        o0 = __builtin_amdgcn_mfma_f32_32x32x16_bf16(vf, f1.v, o0, 0, 0, 0);
        vf = *(const bf16x8*)swz(vc, 32 + l31, scb + hi * 16);
        o1 = __builtin_amdgcn_mfma_f32_32x32x16_bf16(vf, f0.v, o1, 0, 0, 0);
        vf = *(const bf16x8*)swz(vc, 32 + l31, scb + 32 + hi * 16);
        o1 = __builtin_amdgcn_mfma_f32_32x32x16_bf16(vf, f1.v, o1, 0, 0, 0);
      }
      __builtin_amdgcn_s_setprio(0);
    }

    __syncthreads();  // drains vmcnt (next tile landed) + gates buf reuse
    cur ^= 1;
  }

  // l-sum: lane and lane^32 hold complementary k-halves of the same q
  float la = la0 + la1 + la2 + la3;
  la += __shfl_xor(la, 32);
  const float scl = (SPLIT == 1) ? 1.f / la : 1.f;

  if constexpr (SPLIT > 1) {
    if (hi == 0)
      lbuf[(size_t)s * BH_ * N_ + (size_t)bh * N_ + qn + l31] = la;
  }

  // epilogue: per-wave transpose in (now free) smem, coalesced store
  char* ep = smem + wv * 4096;  // per-wave [32 q][64 d]
#pragma unroll
  for (int dt = 0; dt < 2; dt++) {
    const f32x16 o = dt ? o1 : o0;
#pragma unroll
    for (int g = 0; g < 4; g++) {
      bf16x4 o4;
#pragma unroll
      for (int j = 0; j < 4; j++) o4[j] = (__bf16)(o[4 * g + j] * scl);
      *(bf16x4*)swz(ep, l31, dt * 64 + 16 * g + 8 * hi) = o4;
    }
  }
  asm volatile("" ::: "memory");
  {
    __bf16* dst = pO + (size_t)s * PER_ + ((size_t)bh * N_ + qn) * D_;
#pragma unroll
    for (int i = 0; i < 4; i++) {
      const int row = i * 8 + (lane >> 3);
      uint4 v = *(const uint4*)swz(ep, row, (lane & 7) * 16);
      *(uint4*)((char*)dst + i * 1024 + lane * 16) = v;
    }
  }
}

extern "C" void kernel_launch(void* const* d_in, const int* in_sizes, int n_in,
                              void* d_out, int out_size, void* d_ws,
                              size_t ws_size, hipStream_t stream) {
  const float* query = (const float*)d_in[0];
  const float* key_ = (const float*)d_in[1];
  const float* value = (const float*)d_in[2];
  const float* wq = (const float*)d_in[3];
  const float* bq = (const float*)d_in[4];
  const float* wk = (const float*)d_in[5];
  const float* bk = (const float*)d_in[6];
  const float* wv = (const float*)d_in[7];
  const float* bv = (const float*)d_in[8];
  const float* wm = (const float*)d_in[9];
  const float* bm = (const float*)d_in[10];

  // layout: fixed small buffers before the variable-count partials
  __bf16* qb = (__bf16*)d_ws;                 // 8 MB, [bh][n][64]
  char* kbsw = (char*)(qb + PER_);            // 8 MB, swizzled tiles
  char* vtsw = kbsw + PER_ * 2;               // 8 MB, swizzled tiles
  float* lbuf = (float*)(vtsw + PER_ * 2);    // [2][BH][N]
  __bf16* wfq = (__bf16*)(lbuf + 2 * BH_ * N_);
  __bf16* wfk = wfq + 65536;
  __bf16* wfv = wfk + 65536;
  __bf16* wfm = wfv + 65536;
  __bf16* p0 = wfm + 65536;                   // partials: ns x 8 MB

  const size_t fixed = (size_t)((char*)p0 - (char*)d_ws);
  const int ns = (ws_size >= fixed + 2 * PER_ * 2) ? 2 : 1;

  dim3 blk(256);
  W4 wp{wq, wk, wv, wm, wfq, wfk, wfv, wfm};
  wcvt_kernel<<<dim3(32, 4), blk, 0, stream>>>(wp);

  qkv_fused_kernel<<<768, blk, 0, stream>>>(query, key_, value, wfq, wfk, wfv,
                                            bq, bk, bv, qb, kbsw, vtsw);
  if (ns == 2) {
    attn_kernel<2><<<512, dim3(512), 0, stream>>>(qb, kbsw, vtsw, p0, lbuf);
    final_proj_kernel<2><<<1024, blk, 0, stream>>>(p0, lbuf, wfm, bm,
                                                   (float*)d_out);
  } else {
    attn_kernel<1><<<256, dim3(512), 0, stream>>>(qb, kbsw, vtsw, p0, nullptr);
    final_proj_kernel<1><<<1024, blk, 0, stream>>>(p0, nullptr, wfm, bm,
                                                   (float*)d_out);
  }
}

// Round 13
// 101.077 us; speedup vs baseline: 1.1767x; 1.1767x over previous
//
#include <hip/hip_runtime.h>
#include <hip/hip_bf16.h>

typedef float f32x4 __attribute__((ext_vector_type(4)));
typedef float f32x16 __attribute__((ext_vector_type(16)));
typedef __bf16 bf16x8 __attribute__((ext_vector_type(8)));
typedef __bf16 bf16x4 __attribute__((ext_vector_type(4)));
typedef unsigned int uint2v __attribute__((ext_vector_type(2)));
typedef unsigned int u32;

constexpr int B_ = 8, C_ = 256, N_ = 2048, H_ = 4, D_ = 64;
constexpr int BH_ = B_ * H_;  // 32
constexpr size_t PER_ = (size_t)BH_ * N_ * D_;  // 4M elems
constexpr float LOG2E = 1.44269504088896340736f;

static __device__ __forceinline__ float fast_exp2(float x) {
#if __has_builtin(__builtin_amdgcn_exp2f)
  return __builtin_amdgcn_exp2f(x);
#else
  return exp2f(x);
#endif
}

// XOR swizzle for [rows][128B] tiles: spread 16B slots across banks.
static __device__ __forceinline__ void* swz(void* base, int row, int cb) {
  return (char*)base + row * 128 + (cb ^ ((row & 7) << 4));
}
static __device__ __forceinline__ const void* swz(const void* base, int row, int cb) {
  return (const char*)base + row * 128 + (cb ^ ((row & 7) << 4));
}

// async global->LDS, 16B per lane. LDS dst: wave-uniform base + lane*16.
static __device__ __forceinline__ void gload16(void* lds, const void* g) {
  __builtin_amdgcn_global_load_lds(
      (const __attribute__((address_space(1))) u32*)g,
      (__attribute__((address_space(3))) u32*)lds, 16, 0, 0);
}

// ---------------------------------------------------------------------------
// W pre-convert -> bf16 A-fragment order (16x16 frags for the GEMM kernels).
// ---------------------------------------------------------------------------
struct W4 {
  const float* s0; const float* s1; const float* s2; const float* s3;
  __bf16* d0; __bf16* d1; __bf16* d2; __bf16* d3;
};

__global__ __launch_bounds__(256) void wcvt_kernel(W4 p) {
  const int m = blockIdx.y;
  const float* src = m == 0 ? p.s0 : m == 1 ? p.s1 : m == 2 ? p.s2 : p.s3;
  __bf16* dst = m == 0 ? p.d0 : m == 1 ? p.d1 : m == 2 ? p.d2 : p.d3;
  const int f = blockIdx.x * 256 + threadIdx.x;  // 0..8191 fragment ids
  const int o_blk = f >> 9;
  const int ks = (f >> 6) & 7;
  const int lane = f & 63;
  const int row = o_blk * 16 + (lane & 15);
  const int kbase = ks * 32 + (lane >> 4) * 8;
  bf16x8 v;
  if (m == 3) {
    for (int e = 0; e < 8; e++) {
      const int k = kbase + e;
      const int c = ((k & 63) << 2) | (k >> 6);
      v[e] = (__bf16)src[row * 256 + c];
    }
  } else {
    const int srow = ((row & 63) << 2) | (row >> 6);  // orig channel d*4+h
    const float* s = src + srow * 256 + kbase;
    float4 a = *(const float4*)s;
    float4 b = *(const float4*)(s + 4);
    v[0] = (__bf16)a.x; v[1] = (__bf16)a.y; v[2] = (__bf16)a.z; v[3] = (__bf16)a.w;
    v[4] = (__bf16)b.x; v[5] = (__bf16)b.y; v[6] = (__bf16)b.z; v[7] = (__bf16)b.w;
  }
  *(bf16x8*)&dst[(size_t)f * 8] = v;
}

// ---------------------------------------------------------------------------
// Fused QKV projection. X staged transposed in LDS. Staging map: each
// 16-lane group covers one k-row -> 4 x 256B segments per load instruction
// (was 16 x 64B). Q -> row-major [bh][n][64] bf16 (scaled, exp2 dom).
// K,V^T -> PRE-SWIZZLED 8KB tiles (direct scatter stores, round-11 form).
// ---------------------------------------------------------------------------
__global__ __launch_bounds__(256) void qkv_fused_kernel(
    const float* __restrict__ xq, const float* __restrict__ xk,
    const float* __restrict__ xv, const __bf16* __restrict__ wfq,
    const __bf16* __restrict__ wfk, const __bf16* __restrict__ wfv,
    const float* __restrict__ bq, const float* __restrict__ bk,
    const float* __restrict__ bv, __bf16* __restrict__ oq,
    char* __restrict__ oksw, char* __restrict__ ovsw) {
  __shared__ __bf16 xlds[64][264];

  const int m = blockIdx.x >> 8;
  int inner = blockIdx.x & 255;
  inner = (inner & 7) * 32 + (inner >> 3);  // bijective XCD swizzle (256=8*32)
  const int b = inner >> 5, nb = inner & 31;
  const int n0 = nb * 64;

  const float* xf = m == 0 ? xq : m == 1 ? xk : xv;
  const __bf16* wf = m == 0 ? wfq : m == 1 ? wfk : wfv;
  const float* bias = m == 0 ? bq : m == 1 ? bk : bv;
  const float scale = m == 0 ? 0.125f * LOG2E : 1.0f;

  const int t = threadIdx.x;
  {
    const int kl = t >> 4;          // k-pair id 0..15 (4 per wave)
    const int nl = (t & 15) * 4;    // n base: 16 lanes span one 256B row
    const float* src = xf + (size_t)b * C_ * N_ + n0 + nl;
    for (int kp = 0; kp < 8; kp++) {
      const int k = kp * 32 + kl * 2;
      float4 f0 = *(const float4*)(src + (size_t)k * N_);
      float4 f1 = *(const float4*)(src + (size_t)(k + 1) * N_);
      union { __bf16 h[2]; u32 u; } c0, c1, c2, c3;
      c0.h[0] = (__bf16)f0.x; c0.h[1] = (__bf16)f1.x;
      c1.h[0] = (__bf16)f0.y; c1.h[1] = (__bf16)f1.y;
      c2.h[0] = (__bf16)f0.z; c2.h[1] = (__bf16)f1.z;
      c3.h[0] = (__bf16)f0.w; c3.h[1] = (__bf16)f1.w;
      *(u32*)&xlds[nl + 0][k] = c0.u;
      *(u32*)&xlds[nl + 1][k] = c1.u;
      *(u32*)&xlds[nl + 2][k] = c2.u;
      *(u32*)&xlds[nl + 3][k] = c3.u;
    }
  }
  __syncthreads();

  const int lane = t & 63, wvv = t >> 6;
  const int wm = wvv >> 1, wn = wvv & 1;   // wave: 128 o x 32 n
  const int l15 = lane & 15, lg = lane >> 4;

  f32x4 acc[8][2] = {};

  for (int ks = 0; ks < 8; ks++) {
    bf16x8 bfr[2];
    for (int ni = 0; ni < 2; ni++)
      bfr[ni] = *(const bf16x8*)&xlds[wn * 32 + ni * 16 + l15][ks * 32 + lg * 8];
    for (int mi = 0; mi < 8; mi++) {
      bf16x8 af = *(const bf16x8*)&wf[(((size_t)(wm * 8 + mi) * 8 + ks) * 64 + lane) * 8];
      acc[mi][0] = __builtin_amdgcn_mfma_f32_16x16x32_bf16(af, bfr[0], acc[mi][0], 0, 0, 0);
      acc[mi][1] = __builtin_amdgcn_mfma_f32_16x16x32_bf16(af, bfr[1], acc[mi][1], 0, 0, 0);
    }
  }

  for (int mi = 0; mi < 8; mi++) {
    const int h = wm * 2 + (mi >> 2);
    const int d0 = (mi & 3) * 16 + 4 * lg;
    for (int ni = 0; ni < 2; ni++) {
      const int n = n0 + wn * 32 + ni * 16 + l15;
      const size_t tbase = ((size_t)(b * H_ + h) * (N_ / 64) + (n >> 6)) * 8192;
      if (m == 0) {
        bf16x4 o4;
        for (int r = 0; r < 4; r++)
          o4[r] = (__bf16)((acc[mi][ni][r] + bias[((d0 + r) << 2) | h]) * scale);
        *(bf16x4*)&oq[((size_t)(b * H_ + h) * N_ + n) * D_ + d0] = o4;
      } else if (m == 1) {
        bf16x4 o4;
        for (int r = 0; r < 4; r++)
          o4[r] = (__bf16)(acc[mi][ni][r] + bias[((d0 + r) << 2) | h]);
        *(bf16x4*)swz(oksw + tbase, n & 63, 2 * d0) = o4;
      } else {
        for (int r = 0; r < 4; r++)
          *(__bf16*)swz(ovsw + tbase, d0 + r, 2 * (n & 63)) =
              (__bf16)(acc[mi][ni][r] + bias[((d0 + r) << 2) | h]);
      }
    }
  }
}

// ---------------------------------------------------------------------------
// Final projection, NS-way COMBINE fused: xhat = (sum_s p_s)/(sum_s l_s)
// computed in registers per B-fragment. NS==1: p already normalized.
// ---------------------------------------------------------------------------
template <int NS>
__global__ __launch_bounds__(256) void final_proj_kernel(
    const __bf16* __restrict__ p, const float* __restrict__ lb,
    const __bf16* __restrict__ wf, const float* __restrict__ bias,
    float* __restrict__ out) {
  const int bid = blockIdx.x;
  const int wid = (bid & 7) * 128 + (bid >> 3);
  const int o_t = wid & 3;
  const int nb = (wid >> 2) & 31;
  const int b = wid >> 7;
  const int o0 = o_t * 64, n0 = nb * 64;
  const int t = threadIdx.x, lane = t & 63;
  const int wvv = t >> 6, wm = wvv >> 1, wn = wvv & 1;
  const int l15 = lane & 15, lg = lane >> 4;
  const int nbase = n0 + wn * 32 + l15;

  float inv[2][4];  // [ni][h]
  if constexpr (NS > 1) {
    for (int ni = 0; ni < 2; ni++)
      for (int h = 0; h < 4; h++) {
        const size_t bhn = (size_t)(b * H_ + h) * N_ + nbase + ni * 16;
        float ls = 0.f;
#pragma unroll
        for (int u = 0; u < NS; u++) ls += lb[(size_t)u * BH_ * N_ + bhn];
        inv[ni][h] = 1.f / ls;
      }
  }

  f32x4 acc[2][2] = {};

  for (int ks = 0; ks < 8; ks++) {
    bf16x8 af[2];
    for (int mi = 0; mi < 2; mi++)
      af[mi] = *(const bf16x8*)&wf[(((size_t)(o_t * 4 + wm * 2 + mi) * 8 + ks) * 64 + lane) * 8];
    bf16x8 bfr[2];
    const int h = ks >> 1;
    const size_t bh = (size_t)(b * H_ + h);
    const int d0 = (ks & 1) * 32 + lg * 8;
    for (int ni = 0; ni < 2; ni++) {
      const size_t off = (bh * N_ + nbase + ni * 16) * D_ + d0;
      if constexpr (NS == 1) {
        bfr[ni] = *(const bf16x8*)&p[off];
      } else {
        float s8[8] = {};
#pragma unroll
        for (int u = 0; u < NS; u++) {
          bf16x8 a = *(const bf16x8*)&p[(size_t)u * PER_ + off];
#pragma unroll
          for (int e = 0; e < 8; e++) s8[e] += (float)a[e];
        }
        const float iv = inv[ni][h];
        bf16x8 r;
#pragma unroll
        for (int e = 0; e < 8; e++) r[e] = (__bf16)(s8[e] * iv);
        bfr[ni] = r;
      }
    }
    for (int mi = 0; mi < 2; mi++)
      for (int ni = 0; ni < 2; ni++)
        acc[mi][ni] = __builtin_amdgcn_mfma_f32_16x16x32_bf16(
            af[mi], bfr[ni], acc[mi][ni], 0, 0, 0);
  }

  for (int mi = 0; mi < 2; mi++) {
    for (int r = 0; r < 4; r++) {
      const int och = o0 + wm * 32 + mi * 16 + 4 * lg + r;
      const float bv_ = bias[och];
      for (int ni = 0; ni < 2; ni++) {
        const int n = n0 + wn * 32 + ni * 16 + l15;
        out[((size_t)b * C_ + och) * N_ + n] = acc[mi][ni][r] + bv_;
      }
    }
  }
}

// ---------------------------------------------------------------------------
// Flash attention (round-8 proven shape, unchanged): 8 waves x 32 q,
// 512 thr; async global_load_lds from pre-swizzled tiles, double-buffered.
// 32x32 MFMA, in-register P (permlane32_swap), maxless softmax (exp2 dom).
// ---------------------------------------------------------------------------
template <int SPLIT>
__global__ __launch_bounds__(512) void attn_kernel(
    const __bf16* __restrict__ qb, const char* __restrict__ kbsw,
    const char* __restrict__ vtsw, __bf16* __restrict__ pO,
    float* __restrict__ lbuf) {
  __shared__ char smem[32768];  // K dbuf 2x8KB @0, V dbuf 2x8KB @16384

  const int t = threadIdx.x, lane = t & 63, wv = t >> 6;  // wv 0..7
  const int l31 = lane & 31, hi = lane >> 5;

  const int bid = blockIdx.x;  // 256*SPLIT blocks
  const int per_xcd = (256 * SPLIT) / 8;
  const int wid = (bid & 7) * per_xcd + (bid >> 3);  // 4 bh per XCD
  const int bh = wid / (8 * SPLIT);
  const int rem = wid % (8 * SPLIT);
  const int qt = rem % 8;
  const int s = rem / 8;
  const int qn = qt * 256 + wv * 32;  // wave's 32 q rows
  constexpr int NT = N_ / SPLIT / 64; // tiles per block
  const int jt0 = s * NT;

  const char* ktiles = kbsw + (size_t)bh * (N_ / 64) * 8192;
  const char* vtiles = vtsw + (size_t)bh * (N_ / 64) * 8192;

  // Q B-frags: qf[i] = Q[q=qn+l31][d = i*16 + hi*8 .. +7]
  const __bf16* qrow = qb + ((size_t)bh * N_ + qn + l31) * D_;
  bf16x8 qf[4];
#pragma unroll
  for (int i = 0; i < 4; i++) qf[i] = *(const bf16x8*)(qrow + i * 16 + hi * 8);

  // stage tile jt_g into buffer bb (2 async 16B loads/thread, 512 thr)
  auto stage = [&](int jt_g, int bb) {
    gload16(smem + bb * 8192 + t * 16, ktiles + (size_t)jt_g * 8192 + t * 16);
    gload16(smem + 16384 + bb * 8192 + t * 16,
            vtiles + (size_t)jt_g * 8192 + t * 16);
  };

  stage(jt0, 0);
  __syncthreads();  // drains vmcnt -> tile 0 resident

  f32x16 o0 = {}, o1 = {};
  float la0 = 0.f, la1 = 0.f, la2 = 0.f, la3 = 0.f;
  int cur = 0;

  for (int jt = 0; jt < NT; jt++) {
    if (jt + 1 < NT) stage(jt0 + jt + 1, cur ^ 1);
    const char* kc = smem + cur * 8192;
    const char* vc = smem + 16384 + cur * 8192;

    // QK: two 32x32 S-subtiles
    f32x16 s0 = {}, s1 = {};
    __builtin_amdgcn_s_setprio(1);
#pragma unroll
    for (int i = 0; i < 4; i++) {
      bf16x8 kf = *(const bf16x8*)swz(kc, l31, i * 32 + hi * 16);
      s0 = __builtin_amdgcn_mfma_f32_32x32x16_bf16(kf, qf[i], s0, 0, 0, 0);
    }
#pragma unroll
    for (int i = 0; i < 4; i++) {
      bf16x8 kf = *(const bf16x8*)swz(kc, 32 + l31, i * 32 + hi * 16);
      s1 = __builtin_amdgcn_mfma_f32_32x32x16_bf16(kf, qf[i], s1, 0, 0, 0);
    }
    __builtin_amdgcn_s_setprio(0);

    // per-subtile: exp2 -> pack bf16 pairs -> permlane32_swap -> PV
#pragma unroll
    for (int sub = 0; sub < 2; sub++) {
      const f32x16 sv = sub ? s1 : s0;
      float pr[16];
#pragma unroll
      for (int r = 0; r < 16; r++) pr[r] = fast_exp2(sv[r]);
      la0 += pr[0] + pr[4] + pr[8] + pr[12];
      la1 += pr[1] + pr[5] + pr[9] + pr[13];
      la2 += pr[2] + pr[6] + pr[10] + pr[14];
      la3 += pr[3] + pr[7] + pr[11] + pr[15];
      unsigned w[8];
#pragma unroll
      for (int g = 0; g < 8; g++) {
        union { __bf16 h[2]; unsigned u; } cv;
        cv.h[0] = (__bf16)pr[2 * g];
        cv.h[1] = (__bf16)pr[2 * g + 1];
        w[g] = cv.u;
      }
      uint2v r0 = __builtin_amdgcn_permlane32_swap(w[0], w[2], false, false);
      uint2v r1 = __builtin_amdgcn_permlane32_swap(w[1], w[3], false, false);
      uint2v r2 = __builtin_amdgcn_permlane32_swap(w[4], w[6], false, false);
      uint2v r3 = __builtin_amdgcn_permlane32_swap(w[5], w[7], false, false);
      union { unsigned u[4]; bf16x8 v; } f0 = {{r0.x, r1.x, r0.y, r1.y}};  // k 0..15
      union { unsigned u[4]; bf16x8 v; } f1 = {{r2.x, r3.x, r2.y, r3.y}};  // k 16..31
      const int scb = sub * 64;
      __builtin_amdgcn_s_setprio(1);
      {
        bf16x8 vf = *(const bf16x8*)swz(vc, l31, scb + hi * 16);
        o0 = __builtin_amdgcn_mfma_f32_32x32x16_bf16(vf, f0.v, o0, 0, 0, 0);
        vf = *(const bf16x8*)swz(vc, l31, scb + 32 + hi * 16);
        o0 = __builtin_amdgcn_mfma_f32_32x32x16_bf16(vf, f1.v, o0, 0, 0, 0);
        vf = *(const bf16x8*)swz(vc, 32 + l31, scb + hi * 16);
        o1 = __builtin_amdgcn_mfma_f32_32x32x16_bf16(vf, f0.v, o1, 0, 0, 0);
        vf = *(const bf16x8*)swz(vc, 32 + l31, scb + 32 + hi * 16);
        o1 = __builtin_amdgcn_mfma_f32_32x32x16_bf16(vf, f1.v, o1, 0, 0, 0);
      }
      __builtin_amdgcn_s_setprio(0);
    }

    __syncthreads();  // drains vmcnt (next tile landed) + gates buf reuse
    cur ^= 1;
  }

  // l-sum: lane and lane^32 hold complementary k-halves of the same q
  float la = la0 + la1 + la2 + la3;
  la += __shfl_xor(la, 32);
  const float scl = (SPLIT == 1) ? 1.f / la : 1.f;

  if constexpr (SPLIT > 1) {
    if (hi == 0)
      lbuf[(size_t)s * BH_ * N_ + (size_t)bh * N_ + qn + l31] = la;
  }

  // epilogue: per-wave transpose in (now free) smem, coalesced store
  char* ep = smem + wv * 4096;  // per-wave [32 q][64 d]
#pragma unroll
  for (int dt = 0; dt < 2; dt++) {
    const f32x16 o = dt ? o1 : o0;
#pragma unroll
    for (int g = 0; g < 4; g++) {
      bf16x4 o4;
#pragma unroll
      for (int j = 0; j < 4; j++) o4[j] = (__bf16)(o[4 * g + j] * scl);
      *(bf16x4*)swz(ep, l31, dt * 64 + 16 * g + 8 * hi) = o4;
    }
  }
  asm volatile("" ::: "memory");
  {
    __bf16* dst = pO + (size_t)s * PER_ + ((size_t)bh * N_ + qn) * D_;
#pragma unroll
    for (int i = 0; i < 4; i++) {
      const int row = i * 8 + (lane >> 3);
      uint4 v = *(const uint4*)swz(ep, row, (lane & 7) * 16);
      *(uint4*)((char*)dst + i * 1024 + lane * 16) = v;
    }
  }
}

extern "C" void kernel_launch(void* const* d_in, const int* in_sizes, int n_in,
                              void* d_out, int out_size, void* d_ws,
                              size_t ws_size, hipStream_t stream) {
  const float* query = (const float*)d_in[0];
  const float* key_ = (const float*)d_in[1];
  const float* value = (const float*)d_in[2];
  const float* wq = (const float*)d_in[3];
  const float* bq = (const float*)d_in[4];
  const float* wk = (const float*)d_in[5];
  const float* bk = (const float*)d_in[6];
  const float* wv = (const float*)d_in[7];
  const float* bv = (const float*)d_in[8];
  const float* wm = (const float*)d_in[9];
  const float* bm = (const float*)d_in[10];

  // layout: fixed small buffers before the variable-count partials
  __bf16* qb = (__bf16*)d_ws;                 // 8 MB, [bh][n][64]
  char* kbsw = (char*)(qb + PER_);            // 8 MB, swizzled tiles
  char* vtsw = kbsw + PER_ * 2;               // 8 MB, swizzled tiles
  float* lbuf = (float*)(vtsw + PER_ * 2);    // [2][BH][N]
  __bf16* wfq = (__bf16*)(lbuf + 2 * BH_ * N_);
  __bf16* wfk = wfq + 65536;
  __bf16* wfv = wfk + 65536;
  __bf16* wfm = wfv + 65536;
  __bf16* p0 = wfm + 65536;                   // partials: ns x 8 MB

  const size_t fixed = (size_t)((char*)p0 - (char*)d_ws);
  const int ns = (ws_size >= fixed + 2 * PER_ * 2) ? 2 : 1;

  dim3 blk(256);
  W4 wp{wq, wk, wv, wm, wfq, wfk, wfv, wfm};
  wcvt_kernel<<<dim3(32, 4), blk, 0, stream>>>(wp);

  qkv_fused_kernel<<<768, blk, 0, stream>>>(query, key_, value, wfq, wfk, wfv,
                                            bq, bk, bv, qb, kbsw, vtsw);
  if (ns == 2) {
    attn_kernel<2><<<512, dim3(512), 0, stream>>>(qb, kbsw, vtsw, p0, lbuf);
    final_proj_kernel<2><<<1024, blk, 0, stream>>>(p0, lbuf, wfm, bm,
                                                   (float*)d_out);
  } else {
    attn_kernel<1><<<256, dim3(512), 0, stream>>>(qb, kbsw, vtsw, p0, nullptr);
    final_proj_kernel<1><<<1024, blk, 0, stream>>>(p0, nullptr, wfm, bm,
                                                   (float*)d_out);
  }
}

// Round 14
// 99.937 us; speedup vs baseline: 1.1901x; 1.0114x over previous
//
#include <hip/hip_runtime.h>
#include <hip/hip_bf16.h>

typedef float f32x4 __attribute__((ext_vector_type(4)));
typedef float f32x16 __attribute__((ext_vector_type(16)));
typedef __bf16 bf16x8 __attribute__((ext_vector_type(8)));
typedef __bf16 bf16x4 __attribute__((ext_vector_type(4)));
typedef unsigned int uint2v __attribute__((ext_vector_type(2)));
typedef unsigned int u32;

constexpr int B_ = 8, C_ = 256, N_ = 2048, H_ = 4, D_ = 64;
constexpr int BH_ = B_ * H_;  // 32
constexpr size_t PER_ = (size_t)BH_ * N_ * D_;  // 4M elems
constexpr float LOG2E = 1.44269504088896340736f;

static __device__ __forceinline__ float fast_exp2(float x) {
#if __has_builtin(__builtin_amdgcn_exp2f)
  return __builtin_amdgcn_exp2f(x);
#else
  return exp2f(x);
#endif
}

// XOR swizzle for [rows][128B] tiles: spread 16B slots across banks.
static __device__ __forceinline__ void* swz(void* base, int row, int cb) {
  return (char*)base + row * 128 + (cb ^ ((row & 7) << 4));
}
static __device__ __forceinline__ const void* swz(const void* base, int row, int cb) {
  return (const char*)base + row * 128 + (cb ^ ((row & 7) << 4));
}

// async global->LDS, 16B per lane. LDS dst: wave-uniform base + lane*16.
static __device__ __forceinline__ void gload16(void* lds, const void* g) {
  __builtin_amdgcn_global_load_lds(
      (const __attribute__((address_space(1))) u32*)g,
      (__attribute__((address_space(3))) u32*)lds, 16, 0, 0);
}

// ---------------------------------------------------------------------------
// W pre-convert -> bf16 A-fragment order (16x16 frags for the GEMM kernels).
// ---------------------------------------------------------------------------
struct W4 {
  const float* s0; const float* s1; const float* s2; const float* s3;
  __bf16* d0; __bf16* d1; __bf16* d2; __bf16* d3;
};

__global__ __launch_bounds__(256) void wcvt_kernel(W4 p) {
  const int m = blockIdx.y;
  const float* src = m == 0 ? p.s0 : m == 1 ? p.s1 : m == 2 ? p.s2 : p.s3;
  __bf16* dst = m == 0 ? p.d0 : m == 1 ? p.d1 : m == 2 ? p.d2 : p.d3;
  const int f = blockIdx.x * 256 + threadIdx.x;  // 0..8191 fragment ids
  const int o_blk = f >> 9;
  const int ks = (f >> 6) & 7;
  const int lane = f & 63;
  const int row = o_blk * 16 + (lane & 15);
  const int kbase = ks * 32 + (lane >> 4) * 8;
  bf16x8 v;
  if (m == 3) {
    for (int e = 0; e < 8; e++) {
      const int k = kbase + e;
      const int c = ((k & 63) << 2) | (k >> 6);
      v[e] = (__bf16)src[row * 256 + c];
    }
  } else {
    const int srow = ((row & 63) << 2) | (row >> 6);  // orig channel d*4+h
    const float* s = src + srow * 256 + kbase;
    float4 a = *(const float4*)s;
    float4 b = *(const float4*)(s + 4);
    v[0] = (__bf16)a.x; v[1] = (__bf16)a.y; v[2] = (__bf16)a.z; v[3] = (__bf16)a.w;
    v[4] = (__bf16)b.x; v[5] = (__bf16)b.y; v[6] = (__bf16)b.z; v[7] = (__bf16)b.w;
  }
  *(bf16x8*)&dst[(size_t)f * 8] = v;
}

// ---------------------------------------------------------------------------
// Fused QKV projection. Staging is TWO-PHASE: (1) issue all 16 float4 loads
// into register arrays (one vmcnt burst, ~1 HBM round-trip instead of 8),
// (2) pack -> LDS transposed [n][k]. Q -> row-major [bh][n][64] (scaled,
// exp2 dom). K,V^T -> PRE-SWIZZLED 8KB tiles (direct scatter stores).
// ---------------------------------------------------------------------------
__global__ __launch_bounds__(256) void qkv_fused_kernel(
    const float* __restrict__ xq, const float* __restrict__ xk,
    const float* __restrict__ xv, const __bf16* __restrict__ wfq,
    const __bf16* __restrict__ wfk, const __bf16* __restrict__ wfv,
    const float* __restrict__ bq, const float* __restrict__ bk,
    const float* __restrict__ bv, __bf16* __restrict__ oq,
    char* __restrict__ oksw, char* __restrict__ ovsw) {
  __shared__ __bf16 xlds[64][264];

  const int m = blockIdx.x >> 8;
  int inner = blockIdx.x & 255;
  inner = (inner & 7) * 32 + (inner >> 3);  // bijective XCD swizzle (256=8*32)
  const int b = inner >> 5, nb = inner & 31;
  const int n0 = nb * 64;

  const float* xf = m == 0 ? xq : m == 1 ? xk : xv;
  const __bf16* wf = m == 0 ? wfq : m == 1 ? wfk : wfv;
  const float* bias = m == 0 ? bq : m == 1 ? bk : bv;
  const float scale = m == 0 ? 0.125f * LOG2E : 1.0f;

  const int t = threadIdx.x;
  {
    const int kl = t >> 4;          // k-pair id 0..15 (4 per wave)
    const int nl = (t & 15) * 4;    // n base: 16 lanes span one 256B row
    const float* src = xf + (size_t)b * C_ * N_ + n0 + nl;
    float4 f0[8], f1[8];
#pragma unroll
    for (int kp = 0; kp < 8; kp++) {
      const int k = kp * 32 + kl * 2;
      f0[kp] = *(const float4*)(src + (size_t)k * N_);
      f1[kp] = *(const float4*)(src + (size_t)(k + 1) * N_);
    }
#pragma unroll
    for (int kp = 0; kp < 8; kp++) {
      const int k = kp * 32 + kl * 2;
      union { __bf16 h[2]; u32 u; } c0, c1, c2, c3;
      c0.h[0] = (__bf16)f0[kp].x; c0.h[1] = (__bf16)f1[kp].x;
      c1.h[0] = (__bf16)f0[kp].y; c1.h[1] = (__bf16)f1[kp].y;
      c2.h[0] = (__bf16)f0[kp].z; c2.h[1] = (__bf16)f1[kp].z;
      c3.h[0] = (__bf16)f0[kp].w; c3.h[1] = (__bf16)f1[kp].w;
      *(u32*)&xlds[nl + 0][k] = c0.u;
      *(u32*)&xlds[nl + 1][k] = c1.u;
      *(u32*)&xlds[nl + 2][k] = c2.u;
      *(u32*)&xlds[nl + 3][k] = c3.u;
    }
  }
  __syncthreads();

  const int lane = t & 63, wvv = t >> 6;
  const int wm = wvv >> 1, wn = wvv & 1;   // wave: 128 o x 32 n
  const int l15 = lane & 15, lg = lane >> 4;

  f32x4 acc[8][2] = {};

  for (int ks = 0; ks < 8; ks++) {
    bf16x8 bfr[2];
    for (int ni = 0; ni < 2; ni++)
      bfr[ni] = *(const bf16x8*)&xlds[wn * 32 + ni * 16 + l15][ks * 32 + lg * 8];
    for (int mi = 0; mi < 8; mi++) {
      bf16x8 af = *(const bf16x8*)&wf[(((size_t)(wm * 8 + mi) * 8 + ks) * 64 + lane) * 8];
      acc[mi][0] = __builtin_amdgcn_mfma_f32_16x16x32_bf16(af, bfr[0], acc[mi][0], 0, 0, 0);
      acc[mi][1] = __builtin_amdgcn_mfma_f32_16x16x32_bf16(af, bfr[1], acc[mi][1], 0, 0, 0);
    }
  }

  for (int mi = 0; mi < 8; mi++) {
    const int h = wm * 2 + (mi >> 2);
    const int d0 = (mi & 3) * 16 + 4 * lg;
    for (int ni = 0; ni < 2; ni++) {
      const int n = n0 + wn * 32 + ni * 16 + l15;
      const size_t tbase = ((size_t)(b * H_ + h) * (N_ / 64) + (n >> 6)) * 8192;
      if (m == 0) {
        bf16x4 o4;
        for (int r = 0; r < 4; r++)
          o4[r] = (__bf16)((acc[mi][ni][r] + bias[((d0 + r) << 2) | h]) * scale);
        *(bf16x4*)&oq[((size_t)(b * H_ + h) * N_ + n) * D_ + d0] = o4;
      } else if (m == 1) {
        bf16x4 o4;
        for (int r = 0; r < 4; r++)
          o4[r] = (__bf16)(acc[mi][ni][r] + bias[((d0 + r) << 2) | h]);
        *(bf16x4*)swz(oksw + tbase, n & 63, 2 * d0) = o4;
      } else {
        for (int r = 0; r < 4; r++)
          *(__bf16*)swz(ovsw + tbase, d0 + r, 2 * (n & 63)) =
              (__bf16)(acc[mi][ni][r] + bias[((d0 + r) << 2) | h]);
      }
    }
  }
}

// ---------------------------------------------------------------------------
// Final projection, NS-way COMBINE fused: xhat = (sum_s p_s)/(sum_s l_s)
// computed in registers per B-fragment. NS==1: p already normalized.
// ---------------------------------------------------------------------------
template <int NS>
__global__ __launch_bounds__(256) void final_proj_kernel(
    const __bf16* __restrict__ p, const float* __restrict__ lb,
    const __bf16* __restrict__ wf, const float* __restrict__ bias,
    float* __restrict__ out) {
  const int bid = blockIdx.x;
  const int wid = (bid & 7) * 128 + (bid >> 3);
  const int o_t = wid & 3;
  const int nb = (wid >> 2) & 31;
  const int b = wid >> 7;
  const int o0 = o_t * 64, n0 = nb * 64;
  const int t = threadIdx.x, lane = t & 63;
  const int wvv = t >> 6, wm = wvv >> 1, wn = wvv & 1;
  const int l15 = lane & 15, lg = lane >> 4;
  const int nbase = n0 + wn * 32 + l15;

  float inv[2][4];  // [ni][h]
  if constexpr (NS > 1) {
    for (int ni = 0; ni < 2; ni++)
      for (int h = 0; h < 4; h++) {
        const size_t bhn = (size_t)(b * H_ + h) * N_ + nbase + ni * 16;
        float ls = 0.f;
#pragma unroll
        for (int u = 0; u < NS; u++) ls += lb[(size_t)u * BH_ * N_ + bhn];
        inv[ni][h] = 1.f / ls;
      }
  }

  f32x4 acc[2][2] = {};

  for (int ks = 0; ks < 8; ks++) {
    bf16x8 af[2];
    for (int mi = 0; mi < 2; mi++)
      af[mi] = *(const bf16x8*)&wf[(((size_t)(o_t * 4 + wm * 2 + mi) * 8 + ks) * 64 + lane) * 8];
    bf16x8 bfr[2];
    const int h = ks >> 1;
    const size_t bh = (size_t)(b * H_ + h);
    const int d0 = (ks & 1) * 32 + lg * 8;
    for (int ni = 0; ni < 2; ni++) {
      const size_t off = (bh * N_ + nbase + ni * 16) * D_ + d0;
      if constexpr (NS == 1) {
        bfr[ni] = *(const bf16x8*)&p[off];
      } else {
        float s8[8] = {};
#pragma unroll
        for (int u = 0; u < NS; u++) {
          bf16x8 a = *(const bf16x8*)&p[(size_t)u * PER_ + off];
#pragma unroll
          for (int e = 0; e < 8; e++) s8[e] += (float)a[e];
        }
        const float iv = inv[ni][h];
        bf16x8 r;
#pragma unroll
        for (int e = 0; e < 8; e++) r[e] = (__bf16)(s8[e] * iv);
        bfr[ni] = r;
      }
    }
    for (int mi = 0; mi < 2; mi++)
      for (int ni = 0; ni < 2; ni++)
        acc[mi][ni] = __builtin_amdgcn_mfma_f32_16x16x32_bf16(
            af[mi], bfr[ni], acc[mi][ni], 0, 0, 0);
  }

  for (int mi = 0; mi < 2; mi++) {
    for (int r = 0; r < 4; r++) {
      const int och = o0 + wm * 32 + mi * 16 + 4 * lg + r;
      const float bv_ = bias[och];
      for (int ni = 0; ni < 2; ni++) {
        const int n = n0 + wn * 32 + ni * 16 + l15;
        out[((size_t)b * C_ + och) * N_ + n] = acc[mi][ni][r] + bv_;
      }
    }
  }
}

// ---------------------------------------------------------------------------
// Flash attention (round-8 proven shape, unchanged): 8 waves x 32 q,
// 512 thr; async global_load_lds from pre-swizzled tiles, double-buffered.
// 32x32 MFMA, in-register P (permlane32_swap), maxless softmax (exp2 dom).
// ---------------------------------------------------------------------------
template <int SPLIT>
__global__ __launch_bounds__(512) void attn_kernel(
    const __bf16* __restrict__ qb, const char* __restrict__ kbsw,
    const char* __restrict__ vtsw, __bf16* __restrict__ pO,
    float* __restrict__ lbuf) {
  __shared__ char smem[32768];  // K dbuf 2x8KB @0, V dbuf 2x8KB @16384

  const int t = threadIdx.x, lane = t & 63, wv = t >> 6;  // wv 0..7
  const int l31 = lane & 31, hi = lane >> 5;

  const int bid = blockIdx.x;  // 256*SPLIT blocks
  const int per_xcd = (256 * SPLIT) / 8;
  const int wid = (bid & 7) * per_xcd + (bid >> 3);  // 4 bh per XCD
  const int bh = wid / (8 * SPLIT);
  const int rem = wid % (8 * SPLIT);
  const int qt = rem % 8;
  const int s = rem / 8;
  const int qn = qt * 256 + wv * 32;  // wave's 32 q rows
  constexpr int NT = N_ / SPLIT / 64; // tiles per block
  const int jt0 = s * NT;

  const char* ktiles = kbsw + (size_t)bh * (N_ / 64) * 8192;
  const char* vtiles = vtsw + (size_t)bh * (N_ / 64) * 8192;

  // Q B-frags: qf[i] = Q[q=qn+l31][d = i*16 + hi*8 .. +7]
  const __bf16* qrow = qb + ((size_t)bh * N_ + qn + l31) * D_;
  bf16x8 qf[4];
#pragma unroll
  for (int i = 0; i < 4; i++) qf[i] = *(const bf16x8*)(qrow + i * 16 + hi * 8);

  // stage tile jt_g into buffer bb (2 async 16B loads/thread, 512 thr)
  auto stage = [&](int jt_g, int bb) {
    gload16(smem + bb * 8192 + t * 16, ktiles + (size_t)jt_g * 8192 + t * 16);
    gload16(smem + 16384 + bb * 8192 + t * 16,
            vtiles + (size_t)jt_g * 8192 + t * 16);
  };

  stage(jt0, 0);
  __syncthreads();  // drains vmcnt -> tile 0 resident

  f32x16 o0 = {}, o1 = {};
  float la0 = 0.f, la1 = 0.f, la2 = 0.f, la3 = 0.f;
  int cur = 0;

  for (int jt = 0; jt < NT; jt++) {
    if (jt + 1 < NT) stage(jt0 + jt + 1, cur ^ 1);
    const char* kc = smem + cur * 8192;
    const char* vc = smem + 16384 + cur * 8192;

    // QK: two 32x32 S-subtiles
    f32x16 s0 = {}, s1 = {};
    __builtin_amdgcn_s_setprio(1);
#pragma unroll
    for (int i = 0; i < 4; i++) {
      bf16x8 kf = *(const bf16x8*)swz(kc, l31, i * 32 + hi * 16);
      s0 = __builtin_amdgcn_mfma_f32_32x32x16_bf16(kf, qf[i], s0, 0, 0, 0);
    }
#pragma unroll
    for (int i = 0; i < 4; i++) {
      bf16x8 kf = *(const bf16x8*)swz(kc, 32 + l31, i * 32 + hi * 16);
      s1 = __builtin_amdgcn_mfma_f32_32x32x16_bf16(kf, qf[i], s1, 0, 0, 0);
    }
    __builtin_amdgcn_s_setprio(0);

    // per-subtile: exp2 -> pack bf16 pairs -> permlane32_swap -> PV
#pragma unroll
    for (int sub = 0; sub < 2; sub++) {
      const f32x16 sv = sub ? s1 : s0;
      float pr[16];
#pragma unroll
      for (int r = 0; r < 16; r++) pr[r] = fast_exp2(sv[r]);
      la0 += pr[0] + pr[4] + pr[8] + pr[12];
      la1 += pr[1] + pr[5] + pr[9] + pr[13];
      la2 += pr[2] + pr[6] + pr[10] + pr[14];
      la3 += pr[3] + pr[7] + pr[11] + pr[15];
      unsigned w[8];
#pragma unroll
      for (int g = 0; g < 8; g++) {
        union { __bf16 h[2]; unsigned u; } cv;
        cv.h[0] = (__bf16)pr[2 * g];
        cv.h[1] = (__bf16)pr[2 * g + 1];
        w[g] = cv.u;
      }
      uint2v r0 = __builtin_amdgcn_permlane32_swap(w[0], w[2], false, false);
      uint2v r1 = __builtin_amdgcn_permlane32_swap(w[1], w[3], false, false);
      uint2v r2 = __builtin_amdgcn_permlane32_swap(w[4], w[6], false, false);
      uint2v r3 = __builtin_amdgcn_permlane32_swap(w[5], w[7], false, false);
      union { unsigned u[4]; bf16x8 v; } f0 = {{r0.x, r1.x, r0.y, r1.y}};  // k 0..15
      union { unsigned u[4]; bf16x8 v; } f1 = {{r2.x, r3.x, r2.y, r3.y}};  // k 16..31
      const int scb = sub * 64;
      __builtin_amdgcn_s_setprio(1);
      {
        bf16x8 vf = *(const bf16x8*)swz(vc, l31, scb + hi * 16);
        o0 = __builtin_amdgcn_mfma_f32_32x32x16_bf16(vf, f0.v, o0, 0, 0, 0);
        vf = *(const bf16x8*)swz(vc, l31, scb + 32 + hi * 16);
        o0 = __builtin_amdgcn_mfma_f32_32x32x16_bf16(vf, f1.v, o0, 0, 0, 0);
        vf = *(const bf16x8*)swz(vc, 32 + l31, scb + hi * 16);
        o1 = __builtin_amdgcn_mfma_f32_32x32x16_bf16(vf, f0.v, o1, 0, 0, 0);
        vf = *(const bf16x8*)swz(vc, 32 + l31, scb + 32 + hi * 16);
        o1 = __builtin_amdgcn_mfma_f32_32x32x16_bf16(vf, f1.v, o1, 0, 0, 0);
      }
      __builtin_amdgcn_s_setprio(0);
    }

    __syncthreads();  // drains vmcnt (next tile landed) + gates buf reuse
    cur ^= 1;
  }

  // l-sum: lane and lane^32 hold complementary k-halves of the same q
  float la = la0 + la1 + la2 + la3;
  la += __shfl_xor(la, 32);
  const float scl = (SPLIT == 1) ? 1.f / la : 1.f;

  if constexpr (SPLIT > 1) {
    if (hi == 0)
      lbuf[(size_t)s * BH_ * N_ + (size_t)bh * N_ + qn + l31] = la;
  }

  // epilogue: per-wave transpose in (now free) smem, coalesced store
  char* ep = smem + wv * 4096;  // per-wave [32 q][64 d]
#pragma unroll
  for (int dt = 0; dt < 2; dt++) {
    const f32x16 o = dt ? o1 : o0;
#pragma unroll
    for (int g = 0; g < 4; g++) {
      bf16x4 o4;
#pragma unroll
      for (int j = 0; j < 4; j++) o4[j] = (__bf16)(o[4 * g + j] * scl);
      *(bf16x4*)swz(ep, l31, dt * 64 + 16 * g + 8 * hi) = o4;
    }
  }
  asm volatile("" ::: "memory");
  {
    __bf16* dst = pO + (size_t)s * PER_ + ((size_t)bh * N_ + qn) * D_;
#pragma unroll
    for (int i = 0; i < 4; i++) {
      const int row = i * 8 + (lane >> 3);
      uint4 v = *(const uint4*)swz(ep, row, (lane & 7) * 16);
      *(uint4*)((char*)dst + i * 1024 + lane * 16) = v;
    }
  }
}

extern "C" void kernel_launch(void* const* d_in, const int* in_sizes, int n_in,
                              void* d_out, int out_size, void* d_ws,
                              size_t ws_size, hipStream_t stream) {
  const float* query = (const float*)d_in[0];
  const float* key_ = (const float*)d_in[1];
  const float* value = (const float*)d_in[2];
  const float* wq = (const float*)d_in[3];
  const float* bq = (const float*)d_in[4];
  const float* wk = (const float*)d_in[5];
  const float* bk = (const float*)d_in[6];
  const float* wv = (const float*)d_in[7];
  const float* bv = (const float*)d_in[8];
  const float* wm = (const float*)d_in[9];
  const float* bm = (const float*)d_in[10];

  // layout: fixed small buffers before the variable-count partials
  __bf16* qb = (__bf16*)d_ws;                 // 8 MB, [bh][n][64]
  char* kbsw = (char*)(qb + PER_);            // 8 MB, swizzled tiles
  char* vtsw = kbsw + PER_ * 2;               // 8 MB, swizzled tiles
  float* lbuf = (float*)(vtsw + PER_ * 2);    // [2][BH][N]
  __bf16* wfq = (__bf16*)(lbuf + 2 * BH_ * N_);
  __bf16* wfk = wfq + 65536;
  __bf16* wfv = wfk + 65536;
  __bf16* wfm = wfv + 65536;
  __bf16* p0 = wfm + 65536;                   // partials: ns x 8 MB

  const size_t fixed = (size_t)((char*)p0 - (char*)d_ws);
  const int ns = (ws_size >= fixed + 2 * PER_ * 2) ? 2 : 1;

  dim3 blk(256);
  W4 wp{wq, wk, wv, wm, wfq, wfk, wfv, wfm};
  wcvt_kernel<<<dim3(32, 4), blk, 0, stream>>>(wp);

  qkv_fused_kernel<<<768, blk, 0, stream>>>(query, key_, value, wfq, wfk, wfv,
                                            bq, bk, bv, qb, kbsw, vtsw);
  if (ns == 2) {
    attn_kernel<2><<<512, dim3(512), 0, stream>>>(qb, kbsw, vtsw, p0, lbuf);
    final_proj_kernel<2><<<1024, blk, 0, stream>>>(p0, lbuf, wfm, bm,
                                                   (float*)d_out);
  } else {
    attn_kernel<1><<<256, dim3(512), 0, stream>>>(qb, kbsw, vtsw, p0, nullptr);
    final_proj_kernel<1><<<1024, blk, 0, stream>>>(p0, nullptr, wfm, bm,
                                                   (float*)d_out);
  }
}

// Round 15
// 97.984 us; speedup vs baseline: 1.2139x; 1.0199x over previous
//
#include <hip/hip_runtime.h>
#include <hip/hip_bf16.h>

typedef float f32x4 __attribute__((ext_vector_type(4)));
typedef float f32x16 __attribute__((ext_vector_type(16)));
typedef __bf16 bf16x8 __attribute__((ext_vector_type(8)));
typedef __bf16 bf16x4 __attribute__((ext_vector_type(4)));
typedef unsigned int uint2v __attribute__((ext_vector_type(2)));
typedef unsigned int u32;

constexpr int B_ = 8, C_ = 256, N_ = 2048, H_ = 4, D_ = 64;
constexpr int BH_ = B_ * H_;  // 32
constexpr size_t PER_ = (size_t)BH_ * N_ * D_;  // 4M elems
constexpr float LOG2E = 1.44269504088896340736f;

static __device__ __forceinline__ float fast_exp2(float x) {
#if __has_builtin(__builtin_amdgcn_exp2f)
  return __builtin_amdgcn_exp2f(x);
#else
  return exp2f(x);
#endif
}

// XOR swizzle for [rows][128B] tiles: spread 16B slots across banks.
static __device__ __forceinline__ void* swz(void* base, int row, int cb) {
  return (char*)base + row * 128 + (cb ^ ((row & 7) << 4));
}
static __device__ __forceinline__ const void* swz(const void* base, int row, int cb) {
  return (const char*)base + row * 128 + (cb ^ ((row & 7) << 4));
}

// async global->LDS, 16B per lane. LDS dst: wave-uniform base + lane*16.
static __device__ __forceinline__ void gload16(void* lds, const void* g) {
  __builtin_amdgcn_global_load_lds(
      (const __attribute__((address_space(1))) u32*)g,
      (__attribute__((address_space(3))) u32*)lds, 16, 0, 0);
}

// ---------------------------------------------------------------------------
// W pre-convert -> bf16 A-fragment order (16x16 frags for the GEMM kernels).
// ---------------------------------------------------------------------------
struct W4 {
  const float* s0; const float* s1; const float* s2; const float* s3;
  __bf16* d0; __bf16* d1; __bf16* d2; __bf16* d3;
};

__global__ __launch_bounds__(256) void wcvt_kernel(W4 p) {
  const int m = blockIdx.y;
  const float* src = m == 0 ? p.s0 : m == 1 ? p.s1 : m == 2 ? p.s2 : p.s3;
  __bf16* dst = m == 0 ? p.d0 : m == 1 ? p.d1 : m == 2 ? p.d2 : p.d3;
  const int f = blockIdx.x * 256 + threadIdx.x;  // 0..8191 fragment ids
  const int o_blk = f >> 9;
  const int ks = (f >> 6) & 7;
  const int lane = f & 63;
  const int row = o_blk * 16 + (lane & 15);
  const int kbase = ks * 32 + (lane >> 4) * 8;
  bf16x8 v;
  if (m == 3) {
    for (int e = 0; e < 8; e++) {
      const int k = kbase + e;
      const int c = ((k & 63) << 2) | (k >> 6);
      v[e] = (__bf16)src[row * 256 + c];
    }
  } else {
    const int srow = ((row & 63) << 2) | (row >> 6);  // orig channel d*4+h
    const float* s = src + srow * 256 + kbase;
    float4 a = *(const float4*)s;
    float4 b = *(const float4*)(s + 4);
    v[0] = (__bf16)a.x; v[1] = (__bf16)a.y; v[2] = (__bf16)a.z; v[3] = (__bf16)a.w;
    v[4] = (__bf16)b.x; v[5] = (__bf16)b.y; v[6] = (__bf16)b.z; v[7] = (__bf16)b.w;
  }
  *(bf16x8*)&dst[(size_t)f * 8] = v;
}

// ---------------------------------------------------------------------------
// Fused QKV projection, 32-n tiles (grid 1536, ~5-6 blocks/CU resident for
// latency hiding). X tile [256 k][32 n] staged transposed in LDS via packed
// k-pair b32 writes (two-phase burst). Each of 4 waves owns one full head:
// o' = wv*64 + mi*16 + 4*lg + r  (h = wv, d = o'&63).
// Q -> row-major [bh][n][64] (scaled, exp2 dom).
// K,V^T -> PRE-SWIZZLED 8KB tiles (direct scatter stores).
// ---------------------------------------------------------------------------
__global__ __launch_bounds__(256) void qkv_fused_kernel(
    const float* __restrict__ xq, const float* __restrict__ xk,
    const float* __restrict__ xv, const __bf16* __restrict__ wfq,
    const __bf16* __restrict__ wfk, const __bf16* __restrict__ wfv,
    const float* __restrict__ bq, const float* __restrict__ bk,
    const float* __restrict__ bv, __bf16* __restrict__ oq,
    char* __restrict__ oksw, char* __restrict__ ovsw) {
  __shared__ __bf16 xlds[32][264];

  const int m = blockIdx.x / 512;
  int inner = blockIdx.x & 511;
  inner = (inner & 7) * 64 + (inner >> 3);  // bijective XCD swizzle (512=8*64)
  const int b = inner >> 6, nb = inner & 63;
  const int n0 = nb * 32;

  const float* xf = m == 0 ? xq : m == 1 ? xk : xv;
  const __bf16* wf = m == 0 ? wfq : m == 1 ? wfk : wfv;
  const float* bias = m == 0 ? bq : m == 1 ? bk : bv;
  const float scale = m == 0 ? 0.125f * LOG2E : 1.0f;

  const int t = threadIdx.x;
  {
    const int kl = t >> 3;         // k-pair id 0..31
    const int nl = (t & 7) * 4;    // n base: 8 lanes span one 128B row
    const float* src = xf + (size_t)b * C_ * N_ + n0 + nl;
    float4 f0[4], f1[4];
#pragma unroll
    for (int it = 0; it < 4; it++) {
      const int k = (it * 32 + kl) * 2;
      f0[it] = *(const float4*)(src + (size_t)k * N_);
      f1[it] = *(const float4*)(src + (size_t)(k + 1) * N_);
    }
#pragma unroll
    for (int it = 0; it < 4; it++) {
      const int k = (it * 32 + kl) * 2;
      union { __bf16 h[2]; u32 u; } c0, c1, c2, c3;
      c0.h[0] = (__bf16)f0[it].x; c0.h[1] = (__bf16)f1[it].x;
      c1.h[0] = (__bf16)f0[it].y; c1.h[1] = (__bf16)f1[it].y;
      c2.h[0] = (__bf16)f0[it].z; c2.h[1] = (__bf16)f1[it].z;
      c3.h[0] = (__bf16)f0[it].w; c3.h[1] = (__bf16)f1[it].w;
      *(u32*)&xlds[nl + 0][k] = c0.u;
      *(u32*)&xlds[nl + 1][k] = c1.u;
      *(u32*)&xlds[nl + 2][k] = c2.u;
      *(u32*)&xlds[nl + 3][k] = c3.u;
    }
  }
  __syncthreads();

  const int lane = t & 63, wv = t >> 6;  // wv = head h
  const int l15 = lane & 15, lg = lane >> 4;

  f32x4 acc[4][2] = {};

  for (int ks = 0; ks < 8; ks++) {
    bf16x8 bfr[2];
#pragma unroll
    for (int ni = 0; ni < 2; ni++)
      bfr[ni] = *(const bf16x8*)&xlds[ni * 16 + l15][ks * 32 + lg * 8];
#pragma unroll
    for (int mi = 0; mi < 4; mi++) {
      bf16x8 af = *(const bf16x8*)&wf[(((size_t)(wv * 4 + mi) * 8 + ks) * 64 + lane) * 8];
      acc[mi][0] = __builtin_amdgcn_mfma_f32_16x16x32_bf16(af, bfr[0], acc[mi][0], 0, 0, 0);
      acc[mi][1] = __builtin_amdgcn_mfma_f32_16x16x32_bf16(af, bfr[1], acc[mi][1], 0, 0, 0);
    }
  }

  const int h = wv;
  const size_t tbase0 = ((size_t)(b * H_ + h) * (N_ / 64) + (n0 >> 6)) * 8192;
#pragma unroll
  for (int mi = 0; mi < 4; mi++) {
    const int d0 = mi * 16 + 4 * lg;
#pragma unroll
    for (int ni = 0; ni < 2; ni++) {
      const int n = n0 + ni * 16 + l15;
      if (m == 0) {
        bf16x4 o4;
        for (int r = 0; r < 4; r++)
          o4[r] = (__bf16)((acc[mi][ni][r] + bias[((d0 + r) << 2) | h]) * scale);
        *(bf16x4*)&oq[((size_t)(b * H_ + h) * N_ + n) * D_ + d0] = o4;
      } else if (m == 1) {
        bf16x4 o4;
        for (int r = 0; r < 4; r++)
          o4[r] = (__bf16)(acc[mi][ni][r] + bias[((d0 + r) << 2) | h]);
        *(bf16x4*)swz(oksw + tbase0, n & 63, 2 * d0) = o4;
      } else {
        for (int r = 0; r < 4; r++)
          *(__bf16*)swz(ovsw + tbase0, d0 + r, 2 * (n & 63)) =
              (__bf16)(acc[mi][ni][r] + bias[((d0 + r) << 2) | h]);
      }
    }
  }
}

// ---------------------------------------------------------------------------
// Final projection, NS-way COMBINE fused: xhat = (sum_s p_s)/(sum_s l_s)
// computed in registers per B-fragment. NS==1: p already normalized.
// ---------------------------------------------------------------------------
template <int NS>
__global__ __launch_bounds__(256) void final_proj_kernel(
    const __bf16* __restrict__ p, const float* __restrict__ lb,
    const __bf16* __restrict__ wf, const float* __restrict__ bias,
    float* __restrict__ out) {
  const int bid = blockIdx.x;
  const int wid = (bid & 7) * 128 + (bid >> 3);
  const int o_t = wid & 3;
  const int nb = (wid >> 2) & 31;
  const int b = wid >> 7;
  const int o0 = o_t * 64, n0 = nb * 64;
  const int t = threadIdx.x, lane = t & 63;
  const int wvv = t >> 6, wm = wvv >> 1, wn = wvv & 1;
  const int l15 = lane & 15, lg = lane >> 4;
  const int nbase = n0 + wn * 32 + l15;

  float inv[2][4];  // [ni][h]
  if constexpr (NS > 1) {
    for (int ni = 0; ni < 2; ni++)
      for (int h = 0; h < 4; h++) {
        const size_t bhn = (size_t)(b * H_ + h) * N_ + nbase + ni * 16;
        float ls = 0.f;
#pragma unroll
        for (int u = 0; u < NS; u++) ls += lb[(size_t)u * BH_ * N_ + bhn];
        inv[ni][h] = 1.f / ls;
      }
  }

  f32x4 acc[2][2] = {};

  for (int ks = 0; ks < 8; ks++) {
    bf16x8 af[2];
    for (int mi = 0; mi < 2; mi++)
      af[mi] = *(const bf16x8*)&wf[(((size_t)(o_t * 4 + wm * 2 + mi) * 8 + ks) * 64 + lane) * 8];
    bf16x8 bfr[2];
    const int h = ks >> 1;
    const size_t bh = (size_t)(b * H_ + h);
    const int d0 = (ks & 1) * 32 + lg * 8;
    for (int ni = 0; ni < 2; ni++) {
      const size_t off = (bh * N_ + nbase + ni * 16) * D_ + d0;
      if constexpr (NS == 1) {
        bfr[ni] = *(const bf16x8*)&p[off];
      } else {
        float s8[8] = {};
#pragma unroll
        for (int u = 0; u < NS; u++) {
          bf16x8 a = *(const bf16x8*)&p[(size_t)u * PER_ + off];
#pragma unroll
          for (int e = 0; e < 8; e++) s8[e] += (float)a[e];
        }
        const float iv = inv[ni][h];
        bf16x8 r;
#pragma unroll
        for (int e = 0; e < 8; e++) r[e] = (__bf16)(s8[e] * iv);
        bfr[ni] = r;
      }
    }
    for (int mi = 0; mi < 2; mi++)
      for (int ni = 0; ni < 2; ni++)
        acc[mi][ni] = __builtin_amdgcn_mfma_f32_16x16x32_bf16(
            af[mi], bfr[ni], acc[mi][ni], 0, 0, 0);
  }

  for (int mi = 0; mi < 2; mi++) {
    for (int r = 0; r < 4; r++) {
      const int och = o0 + wm * 32 + mi * 16 + 4 * lg + r;
      const float bv_ = bias[och];
      for (int ni = 0; ni < 2; ni++) {
        const int n = n0 + wn * 32 + ni * 16 + l15;
        out[((size_t)b * C_ + och) * N_ + n] = acc[mi][ni][r] + bv_;
      }
    }
  }
}

// ---------------------------------------------------------------------------
// Flash attention (round-8 proven shape, unchanged): 8 waves x 32 q,
// 512 thr; async global_load_lds from pre-swizzled tiles, double-buffered.
// 32x32 MFMA, in-register P (permlane32_swap), maxless softmax (exp2 dom).
// ---------------------------------------------------------------------------
template <int SPLIT>
__global__ __launch_bounds__(512) void attn_kernel(
    const __bf16* __restrict__ qb, const char* __restrict__ kbsw,
    const char* __restrict__ vtsw, __bf16* __restrict__ pO,
    float* __restrict__ lbuf) {
  __shared__ char smem[32768];  // K dbuf 2x8KB @0, V dbuf 2x8KB @16384

  const int t = threadIdx.x, lane = t & 63, wv = t >> 6;  // wv 0..7
  const int l31 = lane & 31, hi = lane >> 5;

  const int bid = blockIdx.x;  // 256*SPLIT blocks
  const int per_xcd = (256 * SPLIT) / 8;
  const int wid = (bid & 7) * per_xcd + (bid >> 3);  // 4 bh per XCD
  const int bh = wid / (8 * SPLIT);
  const int rem = wid % (8 * SPLIT);
  const int qt = rem % 8;
  const int s = rem / 8;
  const int qn = qt * 256 + wv * 32;  // wave's 32 q rows
  constexpr int NT = N_ / SPLIT / 64; // tiles per block
  const int jt0 = s * NT;

  const char* ktiles = kbsw + (size_t)bh * (N_ / 64) * 8192;
  const char* vtiles = vtsw + (size_t)bh * (N_ / 64) * 8192;

  // Q B-frags: qf[i] = Q[q=qn+l31][d = i*16 + hi*8 .. +7]
  const __bf16* qrow = qb + ((size_t)bh * N_ + qn + l31) * D_;
  bf16x8 qf[4];
#pragma unroll
  for (int i = 0; i < 4; i++) qf[i] = *(const bf16x8*)(qrow + i * 16 + hi * 8);

  // stage tile jt_g into buffer bb (2 async 16B loads/thread, 512 thr)
  auto stage = [&](int jt_g, int bb) {
    gload16(smem + bb * 8192 + t * 16, ktiles + (size_t)jt_g * 8192 + t * 16);
    gload16(smem + 16384 + bb * 8192 + t * 16,
            vtiles + (size_t)jt_g * 8192 + t * 16);
  };

  stage(jt0, 0);
  __syncthreads();  // drains vmcnt -> tile 0 resident

  f32x16 o0 = {}, o1 = {};
  float la0 = 0.f, la1 = 0.f, la2 = 0.f, la3 = 0.f;
  int cur = 0;

  for (int jt = 0; jt < NT; jt++) {
    if (jt + 1 < NT) stage(jt0 + jt + 1, cur ^ 1);
    const char* kc = smem + cur * 8192;
    const char* vc = smem + 16384 + cur * 8192;

    // QK: two 32x32 S-subtiles
    f32x16 s0 = {}, s1 = {};
    __builtin_amdgcn_s_setprio(1);
#pragma unroll
    for (int i = 0; i < 4; i++) {
      bf16x8 kf = *(const bf16x8*)swz(kc, l31, i * 32 + hi * 16);
      s0 = __builtin_amdgcn_mfma_f32_32x32x16_bf16(kf, qf[i], s0, 0, 0, 0);
    }
#pragma unroll
    for (int i = 0; i < 4; i++) {
      bf16x8 kf = *(const bf16x8*)swz(kc, 32 + l31, i * 32 + hi * 16);
      s1 = __builtin_amdgcn_mfma_f32_32x32x16_bf16(kf, qf[i], s1, 0, 0, 0);
    }
    __builtin_amdgcn_s_setprio(0);

    // per-subtile: exp2 -> pack bf16 pairs -> permlane32_swap -> PV
#pragma unroll
    for (int sub = 0; sub < 2; sub++) {
      const f32x16 sv = sub ? s1 : s0;
      float pr[16];
#pragma unroll
      for (int r = 0; r < 16; r++) pr[r] = fast_exp2(sv[r]);
      la0 += pr[0] + pr[4] + pr[8] + pr[12];
      la1 += pr[1] + pr[5] + pr[9] + pr[13];
      la2 += pr[2] + pr[6] + pr[10] + pr[14];
      la3 += pr[3] + pr[7] + pr[11] + pr[15];
      unsigned w[8];
#pragma unroll
      for (int g = 0; g < 8; g++) {
        union { __bf16 h[2]; unsigned u; } cv;
        cv.h[0] = (__bf16)pr[2 * g];
        cv.h[1] = (__bf16)pr[2 * g + 1];
        w[g] = cv.u;
      }
      uint2v r0 = __builtin_amdgcn_permlane32_swap(w[0], w[2], false, false);
      uint2v r1 = __builtin_amdgcn_permlane32_swap(w[1], w[3], false, false);
      uint2v r2 = __builtin_amdgcn_permlane32_swap(w[4], w[6], false, false);
      uint2v r3 = __builtin_amdgcn_permlane32_swap(w[5], w[7], false, false);
      union { unsigned u[4]; bf16x8 v; } f0 = {{r0.x, r1.x, r0.y, r1.y}};  // k 0..15
      union { unsigned u[4]; bf16x8 v; } f1 = {{r2.x, r3.x, r2.y, r3.y}};  // k 16..31
      const int scb = sub * 64;
      __builtin_amdgcn_s_setprio(1);
      {
        bf16x8 vf = *(const bf16x8*)swz(vc, l31, scb + hi * 16);
        o0 = __builtin_amdgcn_mfma_f32_32x32x16_bf16(vf, f0.v, o0, 0, 0, 0);
        vf = *(const bf16x8*)swz(vc, l31, scb + 32 + hi * 16);
        o0 = __builtin_amdgcn_mfma_f32_32x32x16_bf16(vf, f1.v, o0, 0, 0, 0);
        vf = *(const bf16x8*)swz(vc, 32 + l31, scb + hi * 16);
        o1 = __builtin_amdgcn_mfma_f32_32x32x16_bf16(vf, f0.v, o1, 0, 0, 0);
        vf = *(const bf16x8*)swz(vc, 32 + l31, scb + 32 + hi * 16);
        o1 = __builtin_amdgcn_mfma_f32_32x32x16_bf16(vf, f1.v, o1, 0, 0, 0);
      }
      __builtin_amdgcn_s_setprio(0);
    }

    __syncthreads();  // drains vmcnt (next tile landed) + gates buf reuse
    cur ^= 1;
  }

  // l-sum: lane and lane^32 hold complementary k-halves of the same q
  float la = la0 + la1 + la2 + la3;
  la += __shfl_xor(la, 32);
  const float scl = (SPLIT == 1) ? 1.f / la : 1.f;

  if constexpr (SPLIT > 1) {
    if (hi == 0)
      lbuf[(size_t)s * BH_ * N_ + (size_t)bh * N_ + qn + l31] = la;
  }

  // epilogue: per-wave transpose in (now free) smem, coalesced store
  char* ep = smem + wv * 4096;  // per-wave [32 q][64 d]
#pragma unroll
  for (int dt = 0; dt < 2; dt++) {
    const f32x16 o = dt ? o1 : o0;
#pragma unroll
    for (int g = 0; g < 4; g++) {
      bf16x4 o4;
#pragma unroll
      for (int j = 0; j < 4; j++) o4[j] = (__bf16)(o[4 * g + j] * scl);
      *(bf16x4*)swz(ep, l31, dt * 64 + 16 * g + 8 * hi) = o4;
    }
  }
  asm volatile("" ::: "memory");
  {
    __bf16* dst = pO + (size_t)s * PER_ + ((size_t)bh * N_ + qn) * D_;
#pragma unroll
    for (int i = 0; i < 4; i++) {
      const int row = i * 8 + (lane >> 3);
      uint4 v = *(const uint4*)swz(ep, row, (lane & 7) * 16);
      *(uint4*)((char*)dst + i * 1024 + lane * 16) = v;
    }
  }
}

extern "C" void kernel_launch(void* const* d_in, const int* in_sizes, int n_in,
                              void* d_out, int out_size, void* d_ws,
                              size_t ws_size, hipStream_t stream) {
  const float* query = (const float*)d_in[0];
  const float* key_ = (const float*)d_in[1];
  const float* value = (const float*)d_in[2];
  const float* wq = (const float*)d_in[3];
  const float* bq = (const float*)d_in[4];
  const float* wk = (const float*)d_in[5];
  const float* bk = (const float*)d_in[6];
  const float* wv = (const float*)d_in[7];
  const float* bv = (const float*)d_in[8];
  const float* wm = (const float*)d_in[9];
  const float* bm = (const float*)d_in[10];

  // layout: fixed small buffers before the variable-count partials
  __bf16* qb = (__bf16*)d_ws;                 // 8 MB, [bh][n][64]
  char* kbsw = (char*)(qb + PER_);            // 8 MB, swizzled tiles
  char* vtsw = kbsw + PER_ * 2;               // 8 MB, swizzled tiles
  float* lbuf = (float*)(vtsw + PER_ * 2);    // [2][BH][N]
  __bf16* wfq = (__bf16*)(lbuf + 2 * BH_ * N_);
  __bf16* wfk = wfq + 65536;
  __bf16* wfv = wfk + 65536;
  __bf16* wfm = wfv + 65536;
  __bf16* p0 = wfm + 65536;                   // partials: ns x 8 MB

  const size_t fixed = (size_t)((char*)p0 - (char*)d_ws);
  const int ns = (ws_size >= fixed + 2 * PER_ * 2) ? 2 : 1;

  dim3 blk(256);
  W4 wp{wq, wk, wv, wm, wfq, wfk, wfv, wfm};
  wcvt_kernel<<<dim3(32, 4), blk, 0, stream>>>(wp);

  qkv_fused_kernel<<<1536, blk, 0, stream>>>(query, key_, value, wfq, wfk, wfv,
                                             bq, bk, bv, qb, kbsw, vtsw);
  if (ns == 2) {
    attn_kernel<2><<<512, dim3(512), 0, stream>>>(qb, kbsw, vtsw, p0, lbuf);
    final_proj_kernel<2><<<1024, blk, 0, stream>>>(p0, lbuf, wfm, bm,
                                                   (float*)d_out);
  } else {
    attn_kernel<1><<<256, dim3(512), 0, stream>>>(qb, kbsw, vtsw, p0, nullptr);
    final_proj_kernel<1><<<1024, blk, 0, stream>>>(p0, nullptr, wfm, bm,
                                                   (float*)d_out);
  }
}